// Round 8
// baseline (106.049 us; speedup 1.0000x reference)
//
#include <hip/hip_runtime.h>
#include <hip/hip_bf16.h>
#include <math.h>

typedef __bf16 bf16;
typedef _Float16 f16;
typedef __attribute__((ext_vector_type(8))) __bf16 bf16x8;
typedef __attribute__((ext_vector_type(8))) _Float16 f16x8;
typedef __attribute__((ext_vector_type(4))) _Float16 f16x4;
typedef __attribute__((ext_vector_type(4))) float floatx4;

__device__ __forceinline__ void split8(floatx4 a0, floatx4 a1, bf16x8& hi, bf16x8& lo) {
#pragma unroll
    for (int t = 0; t < 4; t++) {
        float v0 = a0[t], v1 = a1[t];
        bf16 h0 = (bf16)v0, h1 = (bf16)v1;
        hi[t] = h0;     lo[t] = (bf16)(v0 - (float)h0);
        hi[t + 4] = h1; lo[t + 4] = (bf16)(v1 - (float)h1);
    }
}

// ---------------- projection: qkv = hs @ Wqkv^T + bqkv (fp32-accurate via bf16 hi/lo split) ----------------
// blocks 0..383: one 16x16 tile per wave -> q f16 [b*s][r], k f16 [b*l][r], vT f16 [b][p][l]
// blocks 384..447: Wc fp32 -> f16 copy (for the attn B-frag build)
__global__ __launch_bounds__(256, 4)
void proj_kernel(const float* __restrict__ hs, const float* __restrict__ Wq,
                 const float* __restrict__ bq, const float* __restrict__ Wc,
                 f16* __restrict__ q_ws, f16* __restrict__ k_ws,
                 f16* __restrict__ vT_ws, f16* __restrict__ Wc_ws)
{
    const int tid = threadIdx.x;
    if (blockIdx.x >= 384) {           // Wc fp32 -> f16
        const int base = (blockIdx.x - 384) * 1024 + tid * 4;
        floatx4 w = *(const floatx4*)(Wc + base);
        f16x4 h;
        h.x = (f16)w.x; h.y = (f16)w.y; h.z = (f16)w.z; h.w = (f16)w.w;
        *(f16x4*)(Wc_ws + base) = h;
        return;
    }
    const int wv = tid >> 6, lane = tid & 63;
    const int quad = lane >> 4, lcol = lane & 15;
    const int wt = blockIdx.x * 4 + wv;          // 0..1535: 32 row-tiles x 48 col-tiles
    const int rt = wt / 48, ct = wt - rt * 48;
    const int row0 = rt * 16, col0 = ct * 16;

    const float* arow = hs + (row0 + lcol) * 256;   // A: m = lcol (bs-row)
    const float* brow = Wq + (col0 + lcol) * 256;   // B: n = lcol (out-col), torch [out,in]

    floatx4 acc = {0.f, 0.f, 0.f, 0.f};
#pragma unroll
    for (int ks = 0; ks < 8; ks++) {
        const int h = ks * 32 + quad * 8;
        floatx4 a0 = *(const floatx4*)(arow + h);
        floatx4 a1 = *(const floatx4*)(arow + h + 4);
        floatx4 b0 = *(const floatx4*)(brow + h);
        floatx4 b1 = *(const floatx4*)(brow + h + 4);
        bf16x8 ahi, alo, bhi, blo;
        split8(a0, a1, ahi, alo);
        split8(b0, b1, bhi, blo);
        acc = __builtin_amdgcn_mfma_f32_16x16x32_bf16(ahi, bhi, acc, 0, 0, 0);
        acc = __builtin_amdgcn_mfma_f32_16x16x32_bf16(ahi, blo, acc, 0, 0, 0);
        acc = __builtin_amdgcn_mfma_f32_16x16x32_bf16(alo, bhi, acc, 0, 0, 0);
    }
    const float bias = bq[col0 + lcol];
    const int col = col0 + lcol, seg = col0 >> 8, jj = col & 255;
#pragma unroll
    for (int r = 0; r < 4; r++) {                   // C: row = quad*4 + r, col = lcol
        const int row = row0 + quad * 4 + r;
        const float val = acc[r] + bias;
        if (seg == 0)      q_ws[row * 256 + jj] = (f16)val;
        else if (seg == 1) k_ws[row * 256 + jj] = (f16)val;
        else               vT_ws[(row >> 8) * 65536 + jj * 256 + (row & 255)] = (f16)val;
    }
}

// ---------------- v8: partial-l attention, 4-s-per-wave fusion (v7 + lh race fix) ----------------
// grid 1024 = b(2) x sg(32: 8 s each) x lq(4) x pt(4). 512 thr = 8 waves = sp(2) x lh(2) x ph(2);
// wave = 4 s x 32 l x 32 p. Density rationale (R6 arithmetic): v6 issued 8 ds_read_b128 per
// 16 MFMAs -> LDS-port-bound 5:1. kf/w8 are s-independent -> 4-s waves reuse each LDS read 4x:
// 4 reads -> 16 MFMAs. Main-loop LDS reads per CU halve. Epilogue vf reads drop 16 -> 4.
// R7 BUG FIX: a wave covers only HALF the l-quarter (lh), so the workspace partial axis must be
// (lq*2+lh) = 8 slots, not 4 — v7 had lh=0/lh=1 waves overwriting the same slot (race, absmax 0.74).
// Merge kernel now sums 8 partials. VGPR ~110 fits (512,2)=128 cap (R1: never arg=4).
// Staging (once, one barrier), XOR swizzle: verbatim v6 (verified). LDS 74 KB -> 2 blocks/CU.
__global__ __launch_bounds__(512, 2)
void attn_partial(const f16* __restrict__ qw, const f16* __restrict__ kw,
                  const f16* __restrict__ vT, const f16* __restrict__ Wc16,
                  float* __restrict__ osum_ws, float* __restrict__ ssum_ws)
{
    __shared__ f16 Klds[64 * 256];      // 32768 B  rows l = lq*64 + r, chunk c holds global chunk c^(r&7)
    __shared__ f16 Wlds[64 * 256];      // 32768 B  rows p = p0 + r, same swizzle
    __shared__ f16 vTlds[64 * 68];      //  8704 B  [p][l] pad-68: b64 reads ~2-way (free)

    const int bid = blockIdx.x;
    const int pt = bid & 3;
    const int lq = (bid >> 2) & 3;
    const int sg = (bid >> 4) & 31;
    const int b  = bid >> 9;
    const int p0 = pt * 64;
    const int l0 = lq * 64;
    const int tid  = threadIdx.x;
    const int wv   = tid >> 6;
    const int lane = tid & 63;
    const int quad = lane >> 4, lcol = lane & 15;
    const int ph = wv & 1, lh = (wv >> 1) & 1, sp = wv >> 2;
    const int s_base = sg * 8 + sp * 4;

    const f16* kbase = kw + b * 65536;
    const f16* vbase = vT + b * 65536;
    const f16* qbase = qw + (b * 256 + s_base) * 256;

    // ---- stage K-quarter [64 l][256 r], swizzled ----
#pragma unroll
    for (int it = 0; it < 4; it++) {
        const int id = it * 512 + tid;
        const int r = id >> 5, c = id & 31;
        const int csrc = c ^ (r & 7);
        *(uint4*)(Klds + r * 256 + c * 8) =
            *(const uint4*)(kbase + (l0 + r) * 256 + csrc * 8);
    }
    // ---- stage Wc tile [64 p][256 r], swizzled ----
#pragma unroll
    for (int it = 0; it < 4; it++) {
        const int id = it * 512 + tid;
        const int r = id >> 5, c = id & 31;
        const int csrc = c ^ (r & 7);
        *(uint4*)(Wlds + r * 256 + c * 8) =
            *(const uint4*)(Wc16 + (p0 + r) * 256 + csrc * 8);
    }
    // ---- stage vT tile [64 p][64 l] into pad-68 rows ----
#pragma unroll
    for (int it = 0; it < 2; it++) {
        const int id = it * 512 + tid;      // 1024 f16x4 chunks
        const int p = id >> 4, c = id & 15;
        *(f16x4*)(vTlds + p * 68 + c * 4) =
            *(const f16x4*)(vbase + (p0 + p) * 256 + l0 + c * 4);
    }
    __syncthreads();                        // the ONLY barrier

    floatx4 acc[4][2][2];                   // [u: s][i: l-16-chunk][j: p-16-chunk]
#pragma unroll
    for (int u = 0; u < 4; u++)
#pragma unroll
        for (int i = 0; i < 2; i++)
#pragma unroll
            for (int j = 0; j < 2; j++)
                acc[u][i][j] = (floatx4){0.f, 0.f, 0.f, 0.f};

#pragma unroll
    for (int kk = 0; kk < 8; kk++) {
        const int rb = kk * 32 + quad * 8;
        const int sw = ((kk * 4 + quad) ^ (lcol & 7)) << 3;     // swizzled k-chunk (row&7 == lcol&7)
        f16x8 qv[4];
#pragma unroll
        for (int u = 0; u < 4; u++)         // 64B lines, L1-hot (each q row re-read 8x)
            qv[u] = *(const f16x8*)(qbase + u * 256 + rb);
        f16x8 kf[2];
#pragma unroll
        for (int i = 0; i < 2; i++)         // A-frag: m = lcol -> l-row
            kf[i] = *(const f16x8*)(Klds + (lh * 32 + i * 16 + lcol) * 256 + sw);
        f16x8 w8[2];
#pragma unroll
        for (int j = 0; j < 2; j++)         // raw Wc row; B-frag built per-s below
            w8[j] = *(const f16x8*)(Wlds + (ph * 32 + j * 16 + lcol) * 256 + sw);
#pragma unroll
        for (int u = 0; u < 4; u++) {
#pragma unroll
            for (int j = 0; j < 2; j++) {
                f16x8 bfr = w8[j] * qv[u];  // B-frag: n = lcol -> p-row (pk_mul)
#pragma unroll
                for (int i = 0; i < 2; i++)
                    acc[u][i][j] = __builtin_amdgcn_mfma_f32_16x16x32_f16(kf[i], bfr, acc[u][i][j], 0, 0, 0);
            }
        }
    }

    // ---- epilogue: P = exp(acc) f32; vf shared across the 4 s; partial os/ss ----
    float os[4][2] = {{0.f,0.f},{0.f,0.f},{0.f,0.f},{0.f,0.f}};
    float ss[4][2] = {{0.f,0.f},{0.f,0.f},{0.f,0.f},{0.f,0.f}};
#pragma unroll
    for (int i = 0; i < 2; i++) {
#pragma unroll
        for (int j = 0; j < 2; j++) {
            // v at (p = p0+ph*32+j*16+lcol, l = l0+lh*32+i*16+quad*4+t), local [p][l] pad-68
            f16x4 vf = *(const f16x4*)(vTlds + (ph * 32 + j * 16 + lcol) * 68 + lh * 32 + i * 16 + quad * 4);
            const float vF0 = (float)vf[0], vF1 = (float)vf[1], vF2 = (float)vf[2], vF3 = (float)vf[3];
#pragma unroll
            for (int u = 0; u < 4; u++) {
                const float P0 = __expf(acc[u][i][j][0]);
                const float P1 = __expf(acc[u][i][j][1]);
                const float P2 = __expf(acc[u][i][j][2]);
                const float P3 = __expf(acc[u][i][j][3]);
                os[u][j] = fmaf(P0, vF0, os[u][j]);
                os[u][j] = fmaf(P1, vF1, os[u][j]);
                os[u][j] = fmaf(P2, vF2, os[u][j]);
                os[u][j] = fmaf(P3, vF3, os[u][j]);
                ss[u][j] += (P0 + P1) + (P2 + P3);
            }
        }
    }

    // ---- quad-butterfly; write partials (4 s, 32 p) for slot (lq*2+lh) to workspace ----
#pragma unroll
    for (int u = 0; u < 4; u++)
#pragma unroll
        for (int j = 0; j < 2; j++) {
            os[u][j] += __shfl_xor(os[u][j], 16);
            os[u][j] += __shfl_xor(os[u][j], 32);
            ss[u][j] += __shfl_xor(ss[u][j], 16);
            ss[u][j] += __shfl_xor(ss[u][j], 32);
        }
    if (quad == 0) {
#pragma unroll
        for (int u = 0; u < 4; u++) {
            // 8 partial slots per (b,s): lq*2 + lh  (v7 omitted lh -> write race)
            const int base = ((b * 256 + s_base + u) * 8 + lq * 2 + lh) * 256 + p0 + ph * 32;
#pragma unroll
            for (int j = 0; j < 2; j++) {
                osum_ws[base + j * 16 + lcol] = os[u][j];
                ssum_ws[base + j * 16 + lcol] = ss[u][j];
            }
        }
    }
}

// ---------------- merge: out[b,s,p] = sum over 8 partial slots ----------------
__global__ __launch_bounds__(256, 4)
void merge_kernel(const float* __restrict__ osum_ws, const float* __restrict__ ssum_ws,
                  float* __restrict__ out)
{
    const int g = blockIdx.x * 256 + threadIdx.x;   // 131072 outputs
    const int p = g & 255, bs = g >> 8;
    const int base = bs * 2048 + p;
    float O = 0.f, S = 0.f;
#pragma unroll
    for (int sl = 0; sl < 8; sl++) {
        O += osum_ws[base + sl * 256];
        S += ssum_ws[base + sl * 256];
    }
    out[g] = O / S;
}

extern "C" void kernel_launch(void* const* d_in, const int* in_sizes, int n_in,
                              void* d_out, int out_size, void* d_ws, size_t ws_size,
                              hipStream_t stream) {
    const float* hs   = (const float*)d_in[0];  // [2,256,256]
    const float* Wqkv = (const float*)d_in[1];  // [768,256]
    const float* bqkv = (const float*)d_in[2];  // [768]
    const float* Wc   = (const float*)d_in[3];  // [256,256]
    // d_in[4] (bc) cancels in softmax over l -> unused.
    float* out = (float*)d_out;

    char* ws = (char*)d_ws;
    f16* q_ws   = (f16*)ws;                      // 256 KB f16 q   [b*s][r]
    f16* k_ws   = (f16*)(ws + 262144);           // 256 KB f16 k   [b*l][r]
    f16* vT_ws  = (f16*)(ws + 524288);           // 256 KB f16 vT  [b][p][l]
    f16* Wc_ws  = (f16*)(ws + 786432);           // 128 KB f16 Wc  [p][r]
    float* osum_ws = (float*)(ws + 1048576);     // 4 MB f32 [b][s][8][p]
    float* ssum_ws = (float*)(ws + 5242880);     // 4 MB f32 [b][s][8][p]

    proj_kernel<<<dim3(448), 256, 0, stream>>>(hs, Wqkv, bqkv, Wc, q_ws, k_ws, vT_ws, Wc_ws);
    attn_partial<<<dim3(1024), 512, 0, stream>>>(q_ws, k_ws, vT_ws, Wc_ws, osum_ws, ssum_ws);
    merge_kernel<<<dim3(512), 256, 0, stream>>>(osum_ws, ssum_ws, out);
}

// Round 9
// 90.416 us; speedup vs baseline: 1.1729x; 1.1729x over previous
//
#include <hip/hip_runtime.h>
#include <hip/hip_bf16.h>
#include <math.h>

typedef __bf16 bf16;
typedef _Float16 f16;
typedef __attribute__((ext_vector_type(8))) __bf16 bf16x8;
typedef __attribute__((ext_vector_type(8))) _Float16 f16x8;
typedef __attribute__((ext_vector_type(4))) _Float16 f16x4;
typedef __attribute__((ext_vector_type(4))) float floatx4;

__device__ __forceinline__ void split8(floatx4 a0, floatx4 a1, bf16x8& hi, bf16x8& lo) {
#pragma unroll
    for (int t = 0; t < 4; t++) {
        float v0 = a0[t], v1 = a1[t];
        bf16 h0 = (bf16)v0, h1 = (bf16)v1;
        hi[t] = h0;     lo[t] = (bf16)(v0 - (float)h0);
        hi[t + 4] = h1; lo[t + 4] = (bf16)(v1 - (float)h1);
    }
}

// ---------------- projection: qkv = hs @ Wqkv^T + bqkv (fp32-accurate via bf16 hi/lo split) ----------------
// blocks 0..383: one 16x16 tile per wave -> q f16 [b*s][r], k f16 [b*l][r], vT f16 [b][p][l]
// blocks 384..447: Wc fp32 -> f16 copy (for the attn B-frag build)
__global__ __launch_bounds__(256, 4)
void proj_kernel(const float* __restrict__ hs, const float* __restrict__ Wq,
                 const float* __restrict__ bq, const float* __restrict__ Wc,
                 f16* __restrict__ q_ws, f16* __restrict__ k_ws,
                 f16* __restrict__ vT_ws, f16* __restrict__ Wc_ws)
{
    const int tid = threadIdx.x;
    if (blockIdx.x >= 384) {           // Wc fp32 -> f16
        const int base = (blockIdx.x - 384) * 1024 + tid * 4;
        floatx4 w = *(const floatx4*)(Wc + base);
        f16x4 h;
        h.x = (f16)w.x; h.y = (f16)w.y; h.z = (f16)w.z; h.w = (f16)w.w;
        *(f16x4*)(Wc_ws + base) = h;
        return;
    }
    const int wv = tid >> 6, lane = tid & 63;
    const int quad = lane >> 4, lcol = lane & 15;
    const int wt = blockIdx.x * 4 + wv;          // 0..1535: 32 row-tiles x 48 col-tiles
    const int rt = wt / 48, ct = wt - rt * 48;
    const int row0 = rt * 16, col0 = ct * 16;

    const float* arow = hs + (row0 + lcol) * 256;   // A: m = lcol (bs-row)
    const float* brow = Wq + (col0 + lcol) * 256;   // B: n = lcol (out-col), torch [out,in]

    floatx4 acc = {0.f, 0.f, 0.f, 0.f};
#pragma unroll
    for (int ks = 0; ks < 8; ks++) {
        const int h = ks * 32 + quad * 8;
        floatx4 a0 = *(const floatx4*)(arow + h);
        floatx4 a1 = *(const floatx4*)(arow + h + 4);
        floatx4 b0 = *(const floatx4*)(brow + h);
        floatx4 b1 = *(const floatx4*)(brow + h + 4);
        bf16x8 ahi, alo, bhi, blo;
        split8(a0, a1, ahi, alo);
        split8(b0, b1, bhi, blo);
        acc = __builtin_amdgcn_mfma_f32_16x16x32_bf16(ahi, bhi, acc, 0, 0, 0);
        acc = __builtin_amdgcn_mfma_f32_16x16x32_bf16(ahi, blo, acc, 0, 0, 0);
        acc = __builtin_amdgcn_mfma_f32_16x16x32_bf16(alo, bhi, acc, 0, 0, 0);
    }
    const float bias = bq[col0 + lcol];
    const int col = col0 + lcol, seg = col0 >> 8, jj = col & 255;
#pragma unroll
    for (int r = 0; r < 4; r++) {                   // C: row = quad*4 + r, col = lcol
        const int row = row0 + quad * 4 + r;
        const float val = acc[r] + bias;
        if (seg == 0)      q_ws[row * 256 + jj] = (f16)val;
        else if (seg == 1) k_ws[row * 256 + jj] = (f16)val;
        else               vT_ws[(row >> 8) * 65536 + jj * 256 + (row & 255)] = (f16)val;
    }
}

// ---------------- v9: partial-l attention, register-safe 2-s fusion ----------------
// grid 1024 = b(2) x sg(32: 8 s each) x lq(4) x pt(4). 512 thr = 8 waves = sp(4) x ph(2);
// wave = 2 s x 64 l (FULL quarter) x 32 p.
// R8 post-mortem: 4-s fusion needed ~130 VGPR > 128 cap -> spill, +16 us. This tests the
// LDS-read-density theory cleanly: per kk, kf[4] + w8[2] = 6 ds_read_b128 -> 16 MFMAs
// (v6: 8 reads/16; v8: 4 reads/16 but spilled). Main-loop LDS-port time -25%; epilogue vf
// reads halve (shared across the 2 s). VGPR: acc[2][4][2]=64 + kf 16 + w8 8 + qv 8 ~ 112 < 128.
// Wave covers the full l-quarter -> partial slots stay (b,s,lq) = 4, merge kernel VERBATIM v6
// (no lh axis, no race surface — the R7 bug class is structurally gone).
// Staging (once, one barrier), XOR swizzle: verbatim v6 (verified). LDS 74 KB -> 2 blocks/CU.
__global__ __launch_bounds__(512, 2)
void attn_partial(const f16* __restrict__ qw, const f16* __restrict__ kw,
                  const f16* __restrict__ vT, const f16* __restrict__ Wc16,
                  float* __restrict__ osum_ws, float* __restrict__ ssum_ws)
{
    __shared__ f16 Klds[64 * 256];      // 32768 B  rows l = lq*64 + r, chunk c holds global chunk c^(r&7)
    __shared__ f16 Wlds[64 * 256];      // 32768 B  rows p = p0 + r, same swizzle
    __shared__ f16 vTlds[64 * 68];      //  8704 B  [p][l] pad-68: b64 reads ~2-way (free)

    const int bid = blockIdx.x;
    const int pt = bid & 3;
    const int lq = (bid >> 2) & 3;
    const int sg = (bid >> 4) & 31;
    const int b  = bid >> 9;
    const int p0 = pt * 64;
    const int l0 = lq * 64;
    const int tid  = threadIdx.x;
    const int wv   = tid >> 6;
    const int lane = tid & 63;
    const int quad = lane >> 4, lcol = lane & 15;
    const int ph = wv & 1, sp = wv >> 1;
    const int s_base = sg * 8 + sp * 2;

    const f16* kbase = kw + b * 65536;
    const f16* vbase = vT + b * 65536;
    const f16* qbase = qw + (b * 256 + s_base) * 256;

    // ---- stage K-quarter [64 l][256 r], swizzled ----
#pragma unroll
    for (int it = 0; it < 4; it++) {
        const int id = it * 512 + tid;
        const int r = id >> 5, c = id & 31;
        const int csrc = c ^ (r & 7);
        *(uint4*)(Klds + r * 256 + c * 8) =
            *(const uint4*)(kbase + (l0 + r) * 256 + csrc * 8);
    }
    // ---- stage Wc tile [64 p][256 r], swizzled ----
#pragma unroll
    for (int it = 0; it < 4; it++) {
        const int id = it * 512 + tid;
        const int r = id >> 5, c = id & 31;
        const int csrc = c ^ (r & 7);
        *(uint4*)(Wlds + r * 256 + c * 8) =
            *(const uint4*)(Wc16 + (p0 + r) * 256 + csrc * 8);
    }
    // ---- stage vT tile [64 p][64 l] into pad-68 rows ----
#pragma unroll
    for (int it = 0; it < 2; it++) {
        const int id = it * 512 + tid;      // 1024 f16x4 chunks
        const int p = id >> 4, c = id & 15;
        *(f16x4*)(vTlds + p * 68 + c * 4) =
            *(const f16x4*)(vbase + (p0 + p) * 256 + l0 + c * 4);
    }
    __syncthreads();                        // the ONLY barrier

    floatx4 acc[2][4][2];                   // [u: s][i: l-16-chunk][j: p-16-chunk]
#pragma unroll
    for (int u = 0; u < 2; u++)
#pragma unroll
        for (int i = 0; i < 4; i++)
#pragma unroll
            for (int j = 0; j < 2; j++)
                acc[u][i][j] = (floatx4){0.f, 0.f, 0.f, 0.f};

#pragma unroll
    for (int kk = 0; kk < 8; kk++) {
        const int rb = kk * 32 + quad * 8;
        const int sw = ((kk * 4 + quad) ^ (lcol & 7)) << 3;     // swizzled k-chunk (row&7 == lcol&7)
        f16x8 qv0 = *(const f16x8*)(qbase + rb);                // 64B lines, L1-hot
        f16x8 qv1 = *(const f16x8*)(qbase + 256 + rb);
        f16x8 kf[4];
#pragma unroll
        for (int i = 0; i < 4; i++)         // A-frag: m = lcol -> l-row (full quarter)
            kf[i] = *(const f16x8*)(Klds + (i * 16 + lcol) * 256 + sw);
        f16x8 w8[2];
#pragma unroll
        for (int j = 0; j < 2; j++)         // raw Wc row; B-frag built per-s below
            w8[j] = *(const f16x8*)(Wlds + (ph * 32 + j * 16 + lcol) * 256 + sw);
#pragma unroll
        for (int j = 0; j < 2; j++) {
            f16x8 bf0 = w8[j] * qv0;        // B-frag: n = lcol -> p-row (pk_mul)
            f16x8 bf1 = w8[j] * qv1;
#pragma unroll
            for (int i = 0; i < 4; i++) {
                acc[0][i][j] = __builtin_amdgcn_mfma_f32_16x16x32_f16(kf[i], bf0, acc[0][i][j], 0, 0, 0);
                acc[1][i][j] = __builtin_amdgcn_mfma_f32_16x16x32_f16(kf[i], bf1, acc[1][i][j], 0, 0, 0);
            }
        }
    }

    // ---- epilogue: P = exp(acc) f32; vf shared across the 2 s; partial os/ss ----
    float os[2][2] = {{0.f,0.f},{0.f,0.f}};
    float ss[2][2] = {{0.f,0.f},{0.f,0.f}};
#pragma unroll
    for (int i = 0; i < 4; i++) {
#pragma unroll
        for (int j = 0; j < 2; j++) {
            // v at (p = p0+ph*32+j*16+lcol, l = l0+i*16+quad*4+t), local [p][l] pad-68
            f16x4 vf = *(const f16x4*)(vTlds + (ph * 32 + j * 16 + lcol) * 68 + i * 16 + quad * 4);
            const float vF0 = (float)vf[0], vF1 = (float)vf[1], vF2 = (float)vf[2], vF3 = (float)vf[3];
#pragma unroll
            for (int u = 0; u < 2; u++) {
                const float P0 = __expf(acc[u][i][j][0]);
                const float P1 = __expf(acc[u][i][j][1]);
                const float P2 = __expf(acc[u][i][j][2]);
                const float P3 = __expf(acc[u][i][j][3]);
                os[u][j] = fmaf(P0, vF0, os[u][j]);
                os[u][j] = fmaf(P1, vF1, os[u][j]);
                os[u][j] = fmaf(P2, vF2, os[u][j]);
                os[u][j] = fmaf(P3, vF3, os[u][j]);
                ss[u][j] += (P0 + P1) + (P2 + P3);
            }
        }
    }

    // ---- quad-butterfly; write partials (2 s, 32 p) for slot lq to workspace ----
#pragma unroll
    for (int u = 0; u < 2; u++)
#pragma unroll
        for (int j = 0; j < 2; j++) {
            os[u][j] += __shfl_xor(os[u][j], 16);
            os[u][j] += __shfl_xor(os[u][j], 32);
            ss[u][j] += __shfl_xor(ss[u][j], 16);
            ss[u][j] += __shfl_xor(ss[u][j], 32);
        }
    if (quad == 0) {
#pragma unroll
        for (int u = 0; u < 2; u++) {
            const int base = ((b * 256 + s_base + u) * 4 + lq) * 256 + p0 + ph * 32;
#pragma unroll
            for (int j = 0; j < 2; j++) {
                osum_ws[base + j * 16 + lcol] = os[u][j];
                ssum_ws[base + j * 16 + lcol] = ss[u][j];
            }
        }
    }
}

// ---------------- merge: out[b,s,p] = sum_lq os / sum_lq ss (verbatim v6) ----------------
__global__ __launch_bounds__(256, 4)
void merge_kernel(const float* __restrict__ osum_ws, const float* __restrict__ ssum_ws,
                  float* __restrict__ out)
{
    const int g = blockIdx.x * 256 + threadIdx.x;   // 131072 outputs
    const int p = g & 255, bs = g >> 8;
    const int base = bs * 1024 + p;
    float O = 0.f, S = 0.f;
#pragma unroll
    for (int lq = 0; lq < 4; lq++) {
        O += osum_ws[base + lq * 256];
        S += ssum_ws[base + lq * 256];
    }
    out[g] = O / S;
}

extern "C" void kernel_launch(void* const* d_in, const int* in_sizes, int n_in,
                              void* d_out, int out_size, void* d_ws, size_t ws_size,
                              hipStream_t stream) {
    const float* hs   = (const float*)d_in[0];  // [2,256,256]
    const float* Wqkv = (const float*)d_in[1];  // [768,256]
    const float* bqkv = (const float*)d_in[2];  // [768]
    const float* Wc   = (const float*)d_in[3];  // [256,256]
    // d_in[4] (bc) cancels in softmax over l -> unused.
    float* out = (float*)d_out;

    char* ws = (char*)d_ws;
    f16* q_ws   = (f16*)ws;                      // 256 KB f16 q   [b*s][r]
    f16* k_ws   = (f16*)(ws + 262144);           // 256 KB f16 k   [b*l][r]
    f16* vT_ws  = (f16*)(ws + 524288);           // 256 KB f16 vT  [b][p][l]
    f16* Wc_ws  = (f16*)(ws + 786432);           // 128 KB f16 Wc  [p][r]
    float* osum_ws = (float*)(ws + 1048576);     // 2 MB f32 [b][s][lq][p]
    float* ssum_ws = (float*)(ws + 3145728);     // 2 MB f32 [b][s][lq][p]

    proj_kernel<<<dim3(448), 256, 0, stream>>>(hs, Wqkv, bqkv, Wc, q_ws, k_ws, vT_ws, Wc_ws);
    attn_partial<<<dim3(1024), 512, 0, stream>>>(q_ws, k_ws, vT_ws, Wc_ws, osum_ws, ssum_ws);
    merge_kernel<<<dim3(512), 256, 0, stream>>>(osum_ws, ssum_ws, out);
}